// Round 9
// baseline (84.111 us; speedup 1.0000x reference)
//
#include <hip/hip_runtime.h>
#include <hip/hip_cooperative_groups.h>
#include <math.h>

#define NKEYS 8192
#define NBINS 128
#define NFREQ 64
#define NKER  3
#define HEADD 128

// Fourier expansion: e^{k(cos d - 1)} = e^-k [I0(k) + 2 sum_m Im(k) cos(m d)]
// kappa <= 1, M=4 truncation ~2e-4 relative (verified: absmax 0.031 vs 0.152).
#define MHARM 4
#define NCH   9                    // {1, cos m, sin m}, m=1..4
#define KDIM  (NCH * NFREQ)        // 576
#define KSTEPS (KDIM / 32)         // 18 MFMA K-steps

// Fragment-order k-mapping (16x16x32 f16 MFMA, verified rounds 3-8):
//   k_global = kt*32 + q*8 + j  (q = lane>>4, j = 0..7)
//   (ch, f) <-> kt = ch*2 + (f>>5), q = (f>>3)&3, j = f&7   (bijective)

typedef _Float16 f16x8 __attribute__((ext_vector_type(8)));
typedef float    f32x4 __attribute__((ext_vector_type(4)));

// ---------------------------------------------------------------------------
// B-coefficient job: one (bin, freq) -> 9 channel coeffs in fragment order.
// Math identical to R8's verified build path.
// ---------------------------------------------------------------------------
__device__ __forceinline__ void coeff_job(
    int gid, const float* __restrict__ refang, const float* __restrict__ mu,
    const float* __restrict__ kappa, const float* __restrict__ weight,
    _Float16* __restrict__ Bswz)
{
    const int b = gid >> 6, f = gid & 63;
    const float rf = refang[f];

    float acc[NCH];
    #pragma unroll
    for (int c = 0; c < NCH; ++c) acc[c] = 0.f;

    #pragma unroll
    for (int k = 0; k < NKER; ++k) {
        const int idx = (b * NFREQ + f) * NKER + k;
        const float me  = mu[idx] + rf;
        const float kap = kappa[idx];
        const float w   = weight[idx];
        const float h = 0.5f * kap, h2 = h * h;
        const float wek = w * __expf(-kap);
        float s1, c1;
        __sincosf(me, &s1, &c1);

        float Im[MHARM + 1];
        float tm = 1.f;                       // h^m / m!
        #pragma unroll
        for (int m = 0; m <= MHARM; ++m) {
            float t = tm, s = tm;
            #pragma unroll
            for (int j = 1; j <= 5; ++j) { t *= h2 / (float)(j * (m + j)); s += t; }
            Im[m] = s;
            tm *= h / (float)(m + 1);
        }

        acc[0] += wek * Im[0];
        float cp = 1.f, sp = 0.f, cc = c1, sc = s1;
        #pragma unroll
        for (int m = 1; m <= MHARM; ++m) {
            const float g = 2.f * wek * Im[m];
            acc[2 * m - 1] += g * cc;
            acc[2 * m]     += g * sc;
            const float cn = fmaf(2.f * c1, cc, -cp);
            const float sn = fmaf(2.f * c1, sc, -sp);
            cp = cc; sp = sc; cc = cn; sc = sn;
        }
    }

    const int g = b >> 4, lc = b & 15;
    const int q = (f >> 3) & 3, j = f & 7;
    #pragma unroll
    for (int c = 0; c < NCH; ++c) {
        const int kt = c * 2 + (f >> 5);
        Bswz[((size_t)(g * KSTEPS + kt) * 64 + q * 16 + lc) * 8 + j] = (_Float16)acc[c];
    }
}

// ---------------------------------------------------------------------------
// GEMM tile: one wave computes rows [rc*16, rc*16+16) x cols [g*16, g*16+16).
// A-features in registers (R6's verified code), B from fragment-order table,
// 18 MFMAs, bias + store. No LDS, no block barriers.
// ---------------------------------------------------------------------------
__device__ __forceinline__ void gemm_tile(
    int rc, int g, int lane, const float* __restrict__ K,
    const _Float16* __restrict__ Bswz, const float* __restrict__ bias,
    float* __restrict__ out)
{
    const int q = lane >> 4, lc = lane & 15;
    const int row = rc * 16 + lc;

    f16x8 afrag[KSTEPS];
    const float* kp = K + (size_t)row * HEADD + q * 16;
    #pragma unroll
    for (int h = 0; h < 2; ++h) {
        const float4* ldp = (const float4*)(kp + h * 64);
        const float4 p0 = ldp[0], p1 = ldp[1], p2 = ldp[2], p3 = ldp[3];
        const float xs[8] = {p0.x, p0.z, p1.x, p1.z, p2.x, p2.z, p3.x, p3.z};
        const float ys[8] = {p0.y, p0.w, p1.y, p1.w, p2.y, p2.w, p3.y, p3.w};
        float mag[8], c1[8], cc[8], sc[8], cp[8], sp[8];
        #pragma unroll
        for (int i = 0; i < 8; ++i) {
            const float m2 = xs[i] * xs[i] + ys[i] * ys[i];
            const float ri = (m2 > 0.f) ? rsqrtf(m2) : 0.f;
            mag[i] = m2 * ri;
            c1[i] = xs[i] * ri;
            const float s1 = ys[i] * ri;
            cp[i] = 1.f; sp[i] = 0.f; cc[i] = c1[i]; sc[i] = s1;
            afrag[h][i] = (_Float16)mag[i];                       // ch 0
        }
        #pragma unroll
        for (int m = 1; m <= MHARM; ++m) {
            #pragma unroll
            for (int i = 0; i < 8; ++i) {
                afrag[(2 * m - 1) * 2 + h][i] = (_Float16)(mag[i] * cc[i]);
                afrag[(2 * m) * 2 + h][i]     = (_Float16)(mag[i] * sc[i]);
                const float cn = fmaf(2.f * c1[i], cc[i], -cp[i]);
                const float sn = fmaf(2.f * c1[i], sc[i], -sp[i]);
                cp[i] = cc[i]; sp[i] = sc[i]; cc[i] = cn; sc[i] = sn;
            }
        }
    }

    const f16x8* bp = (const f16x8*)Bswz + (size_t)g * (KSTEPS * 64) + lane;
    f32x4 acc = {0.f, 0.f, 0.f, 0.f};
    #pragma unroll
    for (int kt = 0; kt < KSTEPS; ++kt) {
        const f16x8 b = bp[kt * 64];                 // contiguous 1 KB per wave
        acc = __builtin_amdgcn_mfma_f32_16x16x32_f16(afrag[kt], b, acc, 0, 0, 0);
    }

    // C/D layout: col = lane&15, row = (lane>>4)*4 + reg
    const int col = g * 16 + lc;
    const float bb = bias[col];
    #pragma unroll
    for (int jj = 0; jj < 4; ++jj)
        out[(size_t)(rc * 16 + q * 4 + jj) * NBINS + col] = acc[jj] + bb;
}

// ---------------------------------------------------------------------------
// Cooperative single-dispatch kernel. Grid 1024 x 256 (4 blocks/CU, 0 LDS,
// <=128 VGPR -> all co-resident). Phase 1: 8 threads/block build 8 B-table
// entries (8192 total, zero redundancy). grid.sync(). Phase 2: pure GEMM.
// Block -> 2 rowchunks x 2 colgroups; wave w -> rc0+(w&1), g0+(w>>1).
// bid&255 = rcpair -> all 4 blocks of a rcpair land on one XCD (256%8==0).
// ---------------------------------------------------------------------------
__global__ __launch_bounds__(256, 4) void fused_coop(
    const float* __restrict__ K,
    const float* __restrict__ refang,
    const float* __restrict__ mu,
    const float* __restrict__ kappa,
    const float* __restrict__ weight,
    const float* __restrict__ bias,
    _Float16* __restrict__ Bswz,
    float* __restrict__ out)
{
    const int tid = threadIdx.x, bid = blockIdx.x;

    if (tid < 8)
        coeff_job((bid << 3) | tid, refang, mu, kappa, weight, Bswz);

    cooperative_groups::this_grid().sync();

    const int lane = tid & 63, w = tid >> 6;
    const int rc = (bid & 255) * 2 + (w & 1);        // rowchunk 0..511
    const int g  = (bid >> 8) * 2 + (w >> 1);        // colgroup 0..7
    gemm_tile(rc, g, lane, K, Bswz, bias, out);
}

// --------- non-cooperative fallback pair (same math, two dispatches) -------
__global__ __launch_bounds__(256) void coeff_kernel(
    const float* __restrict__ refang, const float* __restrict__ mu,
    const float* __restrict__ kappa, const float* __restrict__ weight,
    _Float16* __restrict__ Bswz)
{
    coeff_job(blockIdx.x * 256 + threadIdx.x, refang, mu, kappa, weight, Bswz);
}

__global__ __launch_bounds__(256, 4) void gemm_kernel(
    const float* __restrict__ K, const _Float16* __restrict__ Bswz,
    const float* __restrict__ bias, float* __restrict__ out)
{
    const int tid = threadIdx.x, bid = blockIdx.x;
    const int lane = tid & 63, w = tid >> 6;
    const int rc = (bid & 255) * 2 + (w & 1);
    const int g  = (bid >> 8) * 2 + (w >> 1);
    gemm_tile(rc, g, lane, K, Bswz, bias, out);
}

// ---------------------------------------------------------------------------
// Last-resort fallback (ws too small): direct form, known-correct.
// ---------------------------------------------------------------------------
#define KPB 16
#define FTHREADS 512
#define KPT 4
#define KV_STRIDE (KPB + 1)
#define LOG2E 1.44269504088896340736f

__global__ __launch_bounds__(FTHREADS) void vonmises_fallback(
    const float* __restrict__ K,
    const float* __restrict__ refang,
    const float* __restrict__ mu,
    const float* __restrict__ kappa,
    const float* __restrict__ weight,
    const float* __restrict__ bias,
    float* __restrict__ out)
{
    __shared__ float4 kvlds[NFREQ * KV_STRIDE];
    const int tid  = threadIdx.x;
    const int key0 = blockIdx.x * KPB;

    for (int p = tid; p < KPB * NFREQ; p += FTHREADS) {
        int key = p >> 6, f = p & (NFREQ - 1);
        const float2 xy = *(const float2*)(K + (size_t)(key0 + key) * HEADD + 2 * f);
        float m2 = xy.x * xy.x + xy.y * xy.y;
        float rm = (m2 > 0.f) ? rsqrtf(m2) : 0.f;
        kvlds[f * KV_STRIDE + key] = make_float4(xy.x * rm, xy.y * rm, m2 * rm, 0.f);
    }
    __syncthreads();

    const int bin = tid & (NBINS - 1);
    const int kbase = (tid >> 7) * KPT;
    float acc[KPT] = {0.f, 0.f, 0.f, 0.f};

    for (int f = 0; f < NFREQ; ++f) {
        float4 kv[KPT];
        #pragma unroll
        for (int j = 0; j < KPT; ++j) kv[j] = kvlds[f * KV_STRIDE + kbase + j];
        float wk[KPT] = {0.f, 0.f, 0.f, 0.f};
        #pragma unroll
        for (int k = 0; k < NKER; ++k) {
            int idx = (bin * NFREQ + f) * NKER + k;
            float me = mu[idx] + refang[f];
            float ka = kappa[idx] * LOG2E;
            float s, c;
            __sincosf(me, &s, &c);
            #pragma unroll
            for (int j = 0; j < KPT; ++j) {
                float t = fmaf(kv[j].x, ka * c, fmaf(kv[j].y, ka * s, -ka));
                wk[j] = fmaf(exp2f(t), weight[idx], wk[j]);
            }
        }
        #pragma unroll
        for (int j = 0; j < KPT; ++j) acc[j] = fmaf(wk[j], kv[j].z, acc[j]);
    }
    const float bb = bias[bin];
    #pragma unroll
    for (int j = 0; j < KPT; ++j)
        out[(size_t)(key0 + kbase + j) * NBINS + bin] = acc[j] + bb;
}

// ---------------------------------------------------------------------------
extern "C" void kernel_launch(void* const* d_in, const int* in_sizes, int n_in,
                              void* d_out, int out_size, void* d_ws, size_t ws_size,
                              hipStream_t stream) {
    const float* K      = (const float*)d_in[0];
    const float* refang = (const float*)d_in[1];
    const float* mu     = (const float*)d_in[2];
    const float* kappa  = (const float*)d_in[3];
    const float* weight = (const float*)d_in[4];
    const float* bias   = (const float*)d_in[5];
    float* out = (float*)d_out;

    const size_t need = (size_t)NBINS * KDIM * sizeof(_Float16);   // 144 KiB

    if (ws_size >= need) {
        _Float16* Bswz = (_Float16*)d_ws;
        void* kargs[] = {
            (void*)&K, (void*)&refang, (void*)&mu, (void*)&kappa,
            (void*)&weight, (void*)&bias, (void*)&Bswz, (void*)&out
        };
        hipError_t e = hipLaunchCooperativeKernel(
            (const void*)fused_coop, dim3(1024), dim3(256), kargs, 0, stream);
        if (e != hipSuccess) {
            (void)hipGetLastError();     // clear sticky error, use plain path
            coeff_kernel<<<32, 256, 0, stream>>>(refang, mu, kappa, weight, Bswz);
            gemm_kernel<<<1024, 256, 0, stream>>>(K, Bswz, bias, out);
        }
    } else {
        vonmises_fallback<<<NKEYS / KPB, FTHREADS, 0, stream>>>(
            K, refang, mu, kappa, weight, bias, out);
    }
}

// Round 10
// 21.121 us; speedup vs baseline: 3.9823x; 3.9823x over previous
//
#include <hip/hip_runtime.h>
#include <math.h>

#define NKEYS 8192
#define NBINS 128
#define NFREQ 64
#define NKER  3
#define HEADD 128

// Fourier expansion: e^{k(cos d - 1)} = e^-k [I0(k) + 2 sum_m Im(k) cos(m d)]
// kappa <= 1, M=4 truncation ~2e-4 relative (verified: absmax 0.031 vs 0.152).
#define MHARM 4
#define NCH   9                    // {1, cos m, sin m}, m=1..4
#define KDIM  (NCH * NFREQ)        // 576
#define KSTEPS (KDIM / 32)         // 18 MFMA K-steps

// Fragment-order k-mapping (16x16x32 f16 MFMA, verified rounds 3-9):
//   k_global = kt*32 + q*8 + j  (q = lane>>4, j = 0..7)
//   (ch, f) <-> kt = ch*2 + (f>>5), q = (f>>3)&3, j = f&7   (bijective)

typedef _Float16 f16x8 __attribute__((ext_vector_type(8)));
typedef float    f32x4 __attribute__((ext_vector_type(4)));

// ---------------------------------------------------------------------------
// B-coefficient job: one (bin, freq) -> 9 channel coeffs in fragment order.
// ---------------------------------------------------------------------------
__device__ __forceinline__ void coeff_job(
    int gid, const float* __restrict__ refang, const float* __restrict__ mu,
    const float* __restrict__ kappa, const float* __restrict__ weight,
    _Float16* __restrict__ Bswz)
{
    const int b = gid >> 6, f = gid & 63;
    const float rf = refang[f];

    float acc[NCH];
    #pragma unroll
    for (int c = 0; c < NCH; ++c) acc[c] = 0.f;

    #pragma unroll
    for (int k = 0; k < NKER; ++k) {
        const int idx = (b * NFREQ + f) * NKER + k;
        const float me  = mu[idx] + rf;
        const float kap = kappa[idx];
        const float w   = weight[idx];
        const float h = 0.5f * kap, h2 = h * h;
        const float wek = w * __expf(-kap);
        float s1, c1;
        __sincosf(me, &s1, &c1);

        float Im[MHARM + 1];
        float tm = 1.f;                       // h^m / m!
        #pragma unroll
        for (int m = 0; m <= MHARM; ++m) {
            float t = tm, s = tm;
            #pragma unroll
            for (int j = 1; j <= 5; ++j) { t *= h2 / (float)(j * (m + j)); s += t; }
            Im[m] = s;
            tm *= h / (float)(m + 1);
        }

        acc[0] += wek * Im[0];
        float cp = 1.f, sp = 0.f, cc = c1, sc = s1;
        #pragma unroll
        for (int m = 1; m <= MHARM; ++m) {
            const float g = 2.f * wek * Im[m];
            acc[2 * m - 1] += g * cc;
            acc[2 * m]     += g * sc;
            const float cn = fmaf(2.f * c1, cc, -cp);
            const float sn = fmaf(2.f * c1, sc, -sp);
            cp = cc; sp = sc; cc = cn; sc = sn;
        }
    }

    const int g = b >> 4, lc = b & 15;
    const int q = (f >> 3) & 3, j = f & 7;
    #pragma unroll
    for (int c = 0; c < NCH; ++c) {
        const int kt = c * 2 + (f >> 5);
        Bswz[((size_t)(g * KSTEPS + kt) * 64 + q * 16 + lc) * 8 + j] = (_Float16)acc[c];
    }
}

__global__ __launch_bounds__(256) void coeff_kernel(
    const float* __restrict__ refang, const float* __restrict__ mu,
    const float* __restrict__ kappa, const float* __restrict__ weight,
    _Float16* __restrict__ Bswz)
{
    coeff_job(blockIdx.x * 256 + threadIdx.x, refang, mu, kappa, weight, Bswz);
}

// ---------------------------------------------------------------------------
// GEMM kernel: 1024 blocks x 256 threads (4 waves), 0 LDS, 0 barriers,
// ~52 VGPR (R9 counter). Wave -> 16 rows x 16 cols. A-features computed in
// registers from K (Chebyshev recurrence, no transcendentals); B-fragments
// from the 144 KB L2-resident table (contiguous 1 KB per wave per K-step).
// bid&255 = rcpair; blocks {p, p+256, p+512, p+768} all land on XCD p%8
// (256%8==0) -> K-row reads stay in one XCD's L2.
// ---------------------------------------------------------------------------
__global__ __launch_bounds__(256, 4) void gemm_kernel(
    const float* __restrict__ K, const _Float16* __restrict__ Bswz,
    const float* __restrict__ bias, float* __restrict__ out)
{
    const int tid = threadIdx.x, bid = blockIdx.x;
    const int lane = tid & 63, w = tid >> 6;
    const int rc = (bid & 255) * 2 + (w & 1);        // rowchunk 0..511
    const int g  = (bid >> 8) * 2 + (w >> 1);        // colgroup 0..7

    const int q = lane >> 4, lc = lane & 15;
    const int row = rc * 16 + lc;

    // --- A-features for row `row`, 16 freqs (two halves of 8), in regs ---
    f16x8 afrag[KSTEPS];
    const float* kp = K + (size_t)row * HEADD + q * 16;
    #pragma unroll
    for (int h = 0; h < 2; ++h) {
        const float4* ldp = (const float4*)(kp + h * 64);
        const float4 p0 = ldp[0], p1 = ldp[1], p2 = ldp[2], p3 = ldp[3];
        const float xs[8] = {p0.x, p0.z, p1.x, p1.z, p2.x, p2.z, p3.x, p3.z};
        const float ys[8] = {p0.y, p0.w, p1.y, p1.w, p2.y, p2.w, p3.y, p3.w};
        float mag[8], c1[8], cc[8], sc[8], cp[8], sp[8];
        #pragma unroll
        for (int i = 0; i < 8; ++i) {
            const float m2 = xs[i] * xs[i] + ys[i] * ys[i];
            const float ri = (m2 > 0.f) ? rsqrtf(m2) : 0.f;
            mag[i] = m2 * ri;
            c1[i] = xs[i] * ri;
            const float s1 = ys[i] * ri;
            cp[i] = 1.f; sp[i] = 0.f; cc[i] = c1[i]; sc[i] = s1;
            afrag[h][i] = (_Float16)mag[i];                       // ch 0
        }
        #pragma unroll
        for (int m = 1; m <= MHARM; ++m) {
            #pragma unroll
            for (int i = 0; i < 8; ++i) {
                afrag[(2 * m - 1) * 2 + h][i] = (_Float16)(mag[i] * cc[i]);
                afrag[(2 * m) * 2 + h][i]     = (_Float16)(mag[i] * sc[i]);
                const float cn = fmaf(2.f * c1[i], cc[i], -cp[i]);
                const float sn = fmaf(2.f * c1[i], sc[i], -sp[i]);
                cp[i] = cc[i]; sp[i] = sc[i]; cc[i] = cn; sc[i] = sn;
            }
        }
    }

    // --- GEMM: 18 K-steps, B-frag = contiguous 1 KB per wave per step ---
    const f16x8* bp = (const f16x8*)Bswz + (size_t)g * (KSTEPS * 64) + lane;
    f32x4 acc = {0.f, 0.f, 0.f, 0.f};
    #pragma unroll
    for (int kt = 0; kt < KSTEPS; ++kt) {
        const f16x8 b = bp[kt * 64];
        acc = __builtin_amdgcn_mfma_f32_16x16x32_f16(afrag[kt], b, acc, 0, 0, 0);
    }

    // C/D layout: col = lane&15, row = (lane>>4)*4 + reg
    const int col = g * 16 + lc;
    const float bb = bias[col];
    #pragma unroll
    for (int jj = 0; jj < 4; ++jj)
        out[(size_t)(rc * 16 + q * 4 + jj) * NBINS + col] = acc[jj] + bb;
}

// ---------------------------------------------------------------------------
// Last-resort fallback (ws too small): direct form, known-correct.
// ---------------------------------------------------------------------------
#define KPB 16
#define FTHREADS 512
#define KPT 4
#define KV_STRIDE (KPB + 1)
#define LOG2E 1.44269504088896340736f

__global__ __launch_bounds__(FTHREADS) void vonmises_fallback(
    const float* __restrict__ K,
    const float* __restrict__ refang,
    const float* __restrict__ mu,
    const float* __restrict__ kappa,
    const float* __restrict__ weight,
    const float* __restrict__ bias,
    float* __restrict__ out)
{
    __shared__ float4 kvlds[NFREQ * KV_STRIDE];
    const int tid  = threadIdx.x;
    const int key0 = blockIdx.x * KPB;

    for (int p = tid; p < KPB * NFREQ; p += FTHREADS) {
        int key = p >> 6, f = p & (NFREQ - 1);
        const float2 xy = *(const float2*)(K + (size_t)(key0 + key) * HEADD + 2 * f);
        float m2 = xy.x * xy.x + xy.y * xy.y;
        float rm = (m2 > 0.f) ? rsqrtf(m2) : 0.f;
        kvlds[f * KV_STRIDE + key] = make_float4(xy.x * rm, xy.y * rm, m2 * rm, 0.f);
    }
    __syncthreads();

    const int bin = tid & (NBINS - 1);
    const int kbase = (tid >> 7) * KPT;
    float acc[KPT] = {0.f, 0.f, 0.f, 0.f};

    for (int f = 0; f < NFREQ; ++f) {
        float4 kv[KPT];
        #pragma unroll
        for (int j = 0; j < KPT; ++j) kv[j] = kvlds[f * KV_STRIDE + kbase + j];
        float wk[KPT] = {0.f, 0.f, 0.f, 0.f};
        #pragma unroll
        for (int k = 0; k < NKER; ++k) {
            int idx = (bin * NFREQ + f) * NKER + k;
            float me = mu[idx] + refang[f];
            float ka = kappa[idx] * LOG2E;
            float s, c;
            __sincosf(me, &s, &c);
            #pragma unroll
            for (int j = 0; j < KPT; ++j) {
                float t = fmaf(kv[j].x, ka * c, fmaf(kv[j].y, ka * s, -ka));
                wk[j] = fmaf(exp2f(t), weight[idx], wk[j]);
            }
        }
        #pragma unroll
        for (int j = 0; j < KPT; ++j) acc[j] = fmaf(wk[j], kv[j].z, acc[j]);
    }
    const float bb = bias[bin];
    #pragma unroll
    for (int j = 0; j < KPT; ++j)
        out[(size_t)(key0 + kbase + j) * NBINS + bin] = acc[j] + bb;
}

// ---------------------------------------------------------------------------
extern "C" void kernel_launch(void* const* d_in, const int* in_sizes, int n_in,
                              void* d_out, int out_size, void* d_ws, size_t ws_size,
                              hipStream_t stream) {
    const float* K      = (const float*)d_in[0];
    const float* refang = (const float*)d_in[1];
    const float* mu     = (const float*)d_in[2];
    const float* kappa  = (const float*)d_in[3];
    const float* weight = (const float*)d_in[4];
    const float* bias   = (const float*)d_in[5];
    float* out = (float*)d_out;

    const size_t need = (size_t)NBINS * KDIM * sizeof(_Float16);   // 144 KiB

    if (ws_size >= need) {
        _Float16* Bswz = (_Float16*)d_ws;
        coeff_kernel<<<32, 256, 0, stream>>>(refang, mu, kappa, weight, Bswz);
        gemm_kernel<<<1024, 256, 0, stream>>>(K, Bswz, bias, out);
    } else {
        vonmises_fallback<<<NKEYS / KPB, FTHREADS, 0, stream>>>(
            K, refang, mu, kappa, weight, bias, out);
    }
}